// Round 6
// baseline (2483.077 us; speedup 1.0000x reference)
//
#include <hip/hip_runtime.h>
#include <math.h>

// Problem constants (V,E,H,K,T,B) = (32000, 512, 512, 32, 256, 64)
#define T_STEPS 256
#define BATCH   64
#define HID     512
#define KTAGS   32
#define NEGV    -100000.0f
#define START_TAG 30
#define END_TAG   31

#define NBLK      256
#define SPIN_LIM  (1 << 26)
#define LAYER_DONE  300u
#define POISON_DONE 301u
#define POISON    0xFFFFFFFFFFFFFFFFULL

typedef __attribute__((ext_vector_type(8))) short short8;
typedef __attribute__((ext_vector_type(4))) float f32x4;

union V16 { uint4 u; short8 s; };
union HQ  { unsigned long long q[2]; short8 s; };

static __device__ __forceinline__ unsigned short f2b(float f) {
    unsigned u = __float_as_uint(f);
    return (unsigned short)((u + 0x7fffu + ((u >> 16) & 1u)) >> 16);
}
static __device__ __forceinline__ float b2f(unsigned short us) {
    return __uint_as_float(((unsigned)us) << 16);
}

// ---------------------------------------------------------------------------
// Init: poison h-exchange buffers (8 par x 2 d x 2 bg x 64 nt x 64 u64 = 1MB),
// zero padded flag region, zero d_out. Agent-scope stores.
// ---------------------------------------------------------------------------
__global__ __launch_bounds__(256) void init_zero(unsigned int* __restrict__ flags,
                                                 unsigned long long* __restrict__ hbuf,
                                                 float* __restrict__ out)
{
    int i = blockIdx.x * 256 + threadIdx.x;
    if (i < 131072)
        __hip_atomic_store(hbuf + i, POISON, __ATOMIC_RELAXED, __HIP_MEMORY_SCOPE_AGENT);
    if (i < 16384)
        __hip_atomic_store(flags + i, 0u, __ATOMIC_RELAXED, __HIP_MEMORY_SCOPE_AGENT);
    if (i == 0)
        __hip_atomic_store(out, 0.0f, __ATOMIC_RELAXED, __HIP_MEMORY_SCOPE_AGENT);
}

// ---------------------------------------------------------------------------
// embed fp32 -> bf16 (one-time, 16.4M elements)
// ---------------------------------------------------------------------------
__global__ __launch_bounds__(256) void convert_embed(const float* __restrict__ src,
                                                     unsigned short* __restrict__ dst)
{
    long long i = ((long long)blockIdx.x * 256 + threadIdx.x) * 4;
    if (i >= (long long)32000 * 512) return;
    float4 v = *(const float4*)(src + i);
    ushort4 o;
    o.x = f2b(v.x); o.y = f2b(v.y); o.z = f2b(v.z); o.w = f2b(v.w);
    *(ushort4*)(dst + i) = o;
}

// ---------------------------------------------------------------------------
// Pack Wih|Whh (fp32) into bf16 MFMA B-fragment stream for the
// 64-col-block partition. Stream: [d][nt(64)][kt(KT)][nf(2)][lane(64)][j(8)].
// Block (d,nt) owns h-cols nt*8..nt*8+7 => 32 gate cols; frag nf covers
// block-cols bc = nf*16 + (lane&15), bc -> gate g = bc>>3, cc = bc&7,
// weight row r = g*512 + nt*8 + cc; k = kt*32 + (lane>>4)*8 + j.
// kt<xKt -> Wih, else Whh. Thread t == flat 16B granule => coalesced stores.
// ---------------------------------------------------------------------------
__global__ __launch_bounds__(256) void pack_w(const float* __restrict__ wih,
                                              const float* __restrict__ whh,
                                              int xK,
                                              unsigned short* __restrict__ wpack)
{
    const int xKt = xK >> 5, KT = xKt + 16;
    long long t = (long long)blockIdx.x * 256 + threadIdx.x;
    if (t >= (long long)2 * 64 * KT * 2 * 64) return;
    int lane = (int)(t & 63);
    long long rest = t >> 6;
    int nf = (int)(rest & 1); rest >>= 1;
    int kt = (int)(rest % KT); rest /= KT;
    int nt = (int)(rest % 64);
    int d  = (int)(rest / 64);
    int c = lane & 15, q = lane >> 4;
    int bc = nf * 16 + c;
    int r = (bc >> 3) * 512 + nt * 8 + (bc & 7);
    const float* src;
    if (kt < xKt) src = wih + ((long long)d * 2048 * xK + (long long)r * xK + kt * 32 + q * 8);
    else          src = whh + ((long long)d * 2048 * 512 + (long long)r * 512 + (kt - xKt) * 32 + q * 8);
    float4 v0 = *(const float4*)src;
    float4 v1 = *(const float4*)(src + 4);
    unsigned short o[8] = { f2b(v0.x), f2b(v0.y), f2b(v0.z), f2b(v0.w),
                            f2b(v1.x), f2b(v1.y), f2b(v1.z), f2b(v1.w) };
    *(uint4*)(wpack + t * 8) = *(const uint4*)o;
}

// ---------------------------------------------------------------------------
// One BiLSTM layer's step loop, templated on input width XK.
// ALL weights (X + H) are LDS-resident for the whole layer (L0 64KB,
// L1 96KB): per-step VMEM loads are ONLY the A-rows (8/16) + 16 prime-burst
// h loads -> no L2/HBM weight thrash feeding the straggler-max, primes sit
// directly behind A-loads in the FIFO.
// H phase is chunk-interleaved: validate chunk i (counted vmcnt in FIFO
// order) then MFMA it, so late-arriving producer chunks overlap compute.
// Publish packs h via shfl_xor — data store IS the signal (poison scheme).
// All arithmetic (k-order per acc, reduce order, gate math, pack layout,
// store addresses, atomic scopes) identical to prior passing version.
// ---------------------------------------------------------------------------
template<int XK>
static __device__ __forceinline__ void layer_steps(
    const int d, const int bg, const int nt, const int tid,
    const int* __restrict__ tokens,
    const unsigned short* __restrict__ embB,
    const unsigned short* __restrict__ hs_in,   // L1 input rows (null for L0)
    const unsigned short* __restrict__ wp,      // block's packed weight base
    const float* __restrict__ bia,
    unsigned short* __restrict__ hso,
    unsigned long long* __restrict__ hbuf64,
    uint4* __restrict__ wlds,                   // [KT][2][64] uint4 (LDS)
    float (&Gred)[4][32][33],
    int* __restrict__ tok_s)
{
    constexpr bool L0  = (XK == 512);
    constexpr int  xKt = XK >> 5;
    constexpr int  KT  = xKt + 16;
    constexpr int  nX  = xKt >> 2;             // X-phase kts per wave (4 or 8)

    const int w = tid >> 6, lane = tid & 63;
    const int lm = lane & 15, q = lane >> 4;
    const int brow = tid >> 3, hc = tid & 7;   // gate-phase cell (row, hcol)

    // ALL weights -> LDS (once per layer)
    const uint4* wp4 = (const uint4*)wp;
    for (int j = tid; j < KT * 128; j += 256)
        wlds[j] = wp4[j];

    float breg[4];
    #pragma unroll
    for (int g = 0; g < 4; ++g) breg[g] = bia[g * 512 + nt * 8 + hc];
    float creg = 0.0f;

    __syncthreads();

    for (int s = 0; s < T_STEPS; ++s) {
        const int tt = d ? (T_STEPS - 1 - s) : s;

        if (L0 && tid < 32) tok_s[tid] = tokens[tt * BATCH + bg * 32 + tid];
        __syncthreads();                       // tok ready + Gred WAR

        // A-row base pointers (lane rows mt*16+lm)
        const unsigned short* xr[2];
        #pragma unroll
        for (int mt = 0; mt < 2; ++mt) {
            int m = mt * 16 + lm;
            if (L0) xr[mt] = embB + (long long)tok_s[m] * 512;
            else    xr[mt] = hs_in + ((long long)tt * 64 + bg * 32 + m) * 1024;
        }

        // ---------------- issue ALL A loads (unrolled, in flight) ----------
        uint4 av[nX][2];
        #pragma unroll
        for (int i = 0; i < nX; ++i) {
            const int kt = w * nX + i;
            #pragma unroll
            for (int mt = 0; mt < 2; ++mt)
                av[i][mt] = *(const uint4*)(xr[mt] + kt * 32 + q * 8);
        }

        // ---------------- prime-burst h(s-1) (after A loads in FIFO) -------
        HQ hq[4][2];
        const unsigned long long* hbq =
            hbuf64 + (long long)(((((s - 1) & 7) * 2 + d) * 2 + bg)) * 4096;
        if (s > 0) {
            #pragma unroll
            for (int i = 0; i < 4; ++i) {
                const int kth = w * 4 + i;
                #pragma unroll
                for (int mt = 0; mt < 2; ++mt) {
                    const int base = (kth * 4 + q) * 64 + (mt * 16 + lm) * 2;
                    hq[i][mt].q[0] = __hip_atomic_load(hbq + base,     __ATOMIC_RELAXED, __HIP_MEMORY_SCOPE_AGENT);
                    hq[i][mt].q[1] = __hip_atomic_load(hbq + base + 1, __ATOMIC_RELAXED, __HIP_MEMORY_SCOPE_AGENT);
                }
            }
        }

        // ---------------- X MFMAs (B from LDS; primes stay in flight) ------
        f32x4 acc[2][2];
        #pragma unroll
        for (int mt = 0; mt < 2; ++mt)
            #pragma unroll
            for (int nf = 0; nf < 2; ++nf) acc[mt][nf] = (f32x4)0.0f;

        #pragma unroll
        for (int i = 0; i < nX; ++i) {
            const int kt = w * nX + i;
            V16 a0, a1, b0, b1;
            a0.u = av[i][0]; a1.u = av[i][1];
            b0.u = wlds[(kt * 2 + 0) * 64 + lane];
            b1.u = wlds[(kt * 2 + 1) * 64 + lane];
            acc[0][0] = __builtin_amdgcn_mfma_f32_16x16x32_bf16(a0.s, b0.s, acc[0][0], 0, 0, 0);
            acc[0][1] = __builtin_amdgcn_mfma_f32_16x16x32_bf16(a0.s, b1.s, acc[0][1], 0, 0, 0);
            acc[1][0] = __builtin_amdgcn_mfma_f32_16x16x32_bf16(a1.s, b0.s, acc[1][0], 0, 0, 0);
            acc[1][1] = __builtin_amdgcn_mfma_f32_16x16x32_bf16(a1.s, b1.s, acc[1][1], 0, 0, 0);
        }

        // -------- H phase: per-chunk validate (counted wait) then MFMA -----
        if (s > 0) {
            #pragma unroll
            for (int i = 0; i < 4; ++i) {
                const int kth = w * 4 + i;
                int n = 0;
                for (;;) {
                    int bad = 0;
                    #pragma unroll
                    for (int mt = 0; mt < 2; ++mt) {
                        const int base = (kth * 4 + q) * 64 + (mt * 16 + lm) * 2;
                        if (hq[i][mt].q[0] == POISON) {
                            hq[i][mt].q[0] = __hip_atomic_load(hbq + base,     __ATOMIC_RELAXED, __HIP_MEMORY_SCOPE_AGENT);
                            bad = 1;
                        }
                        if (hq[i][mt].q[1] == POISON) {
                            hq[i][mt].q[1] = __hip_atomic_load(hbq + base + 1, __ATOMIC_RELAXED, __HIP_MEMORY_SCOPE_AGENT);
                            bad = 1;
                        }
                    }
                    if (!bad) break;
                    __builtin_amdgcn_s_sleep(1);
                    if (++n > SPIN_LIM) break;
                }
                V16 b0, b1;
                b0.u = wlds[((xKt + kth) * 2 + 0) * 64 + lane];
                b1.u = wlds[((xKt + kth) * 2 + 1) * 64 + lane];
                acc[0][0] = __builtin_amdgcn_mfma_f32_16x16x32_bf16(hq[i][0].s, b0.s, acc[0][0], 0, 0, 0);
                acc[0][1] = __builtin_amdgcn_mfma_f32_16x16x32_bf16(hq[i][0].s, b1.s, acc[0][1], 0, 0, 0);
                acc[1][0] = __builtin_amdgcn_mfma_f32_16x16x32_bf16(hq[i][1].s, b0.s, acc[1][0], 0, 0, 0);
                acc[1][1] = __builtin_amdgcn_mfma_f32_16x16x32_bf16(hq[i][1].s, b1.s, acc[1][1], 0, 0, 0);
            }
        }

        // ---------------- K-reduce across waves + gates ---------------------
        #pragma unroll
        for (int mt = 0; mt < 2; ++mt)
            #pragma unroll
            for (int nf = 0; nf < 2; ++nf)
                #pragma unroll
                for (int r = 0; r < 4; ++r)
                    Gred[w][nf * 16 + lm][mt * 16 + q * 4 + r] = acc[mt][nf][r];
        __syncthreads();

        float vg[4];
        #pragma unroll
        for (int g = 0; g < 4; ++g) {
            float v = breg[g];
            #pragma unroll
            for (int ww = 0; ww < 4; ++ww) v += Gred[ww][g * 8 + hc][brow];
            vg[g] = v;
        }
        const float si = 1.0f / (1.0f + __expf(-vg[0]));
        const float sf = 1.0f / (1.0f + __expf(-vg[1]));
        const float so = 1.0f / (1.0f + __expf(-vg[3]));
        const float cn = sf * creg + si * tanhf(vg[2]);
        const float hn = so * tanhf(cn);
        creg = cn;

        // ------- publish h via shfl pack (data store IS the signal) --------
        unsigned pv = (unsigned)f2b(hn);
        unsigned p2 = pv | (__shfl_xor(pv, 1) << 16);
        unsigned long long hv = (unsigned long long)p2
                              | ((unsigned long long)__shfl_xor(p2, 2) << 32);
        if ((tid & 3) == 0) {
            const int row = brow, cq = hc >> 2;
            unsigned long long* dst =
                hbuf64 + ((long long)((((s & 7) * 2 + d) * 2 + bg) * 64 + nt)) * 64 + row * 2 + cq;
            __hip_atomic_store(dst, hv, __ATOMIC_RELAXED, __HIP_MEMORY_SCOPE_AGENT);
            *(unsigned long long*)(hso + ((long long)tt * 64 + bg * 32 + row) * 1024
                                       + d * 512 + nt * 8 + cq * 4) = hv;
            unsigned long long* pdst =
                hbuf64 + ((long long)(((((s + 2) & 7) * 2 + d) * 2 + bg) * 64 + nt)) * 64 + row * 2 + cq;
            __hip_atomic_store(pdst, POISON, __ATOMIC_RELAXED, __HIP_MEMORY_SCOPE_AGENT);
        }
        // no per-step drain / flag / 3rd barrier: consumers self-validate
    }
}

// ---------------------------------------------------------------------------
// Persistent BiLSTM, MFMA edition — batch-grouped partition (2d x 2bg x 64nt,
// block owns 32 rows x 8 h-cols), data-is-signal poison exchange, all-LDS
// weights, templated unrolled step loop. Layer boundary: two-phase flag
// barrier + re-poison. LDS: 96KB weights + 16.9KB Gred (1 block/CU).
// ---------------------------------------------------------------------------
__global__ __launch_bounds__(256, 1) void lstm_mfma(
    const int* __restrict__ tokens,
    const unsigned short* __restrict__ embB,   // [32000][512] bf16
    const unsigned short* __restrict__ wp0,    // packed L0 weights
    const unsigned short* __restrict__ wp1,    // packed L1 weights
    const float* __restrict__ bb0, const float* __restrict__ bb1,
    unsigned short* __restrict__ hs0,          // [T][B][1024] bf16
    unsigned short* __restrict__ hs1,
    unsigned long long* __restrict__ hbuf64,   // [8][2][2][64][32][2] u64
    unsigned int* __restrict__ flags)          // 256 x 32 u32 (128B pad/line)
{
    __shared__ uint4 wlds[6144];               // 96KB: [KT<=48][2][64] uint4
    __shared__ float Gred[4][32][33];
    __shared__ int   tok_s[32];

    const int bid = blockIdx.x;
    const int d   = bid >> 7;
    const int bg  = (bid >> 6) & 1;
    const int nt  = bid & 63;
    const int tid = threadIdx.x;

    layer_steps<512>(d, bg, nt, tid, tokens, embB, (const unsigned short*)nullptr,
                     wp0 + (long long)(d * 64 + nt) * 32 * 1024,
                     bb0 + (long long)d * 2048,
                     hs0, hbuf64, wlds, Gred, tok_s);

    // ------------- layer boundary: two-phase barrier ------------------------
    {
        __threadfence();                    // wb dirty hs0 out of local L2
        __syncthreads();
        if (tid == 0)
            __hip_atomic_store(flags + bid * 32, LAYER_DONE,
                               __ATOMIC_RELAXED, __HIP_MEMORY_SCOPE_AGENT);
        if (tid < 64) {                     // phase 1: all 256 blocks done
            int n = 0;
            for (;;) {
                unsigned a = __hip_atomic_load(flags + tid * 32,         __ATOMIC_RELAXED, __HIP_MEMORY_SCOPE_AGENT);
                unsigned b = __hip_atomic_load(flags + (tid + 64) * 32,  __ATOMIC_RELAXED, __HIP_MEMORY_SCOPE_AGENT);
                unsigned c = __hip_atomic_load(flags + (tid + 128) * 32, __ATOMIC_RELAXED, __HIP_MEMORY_SCOPE_AGENT);
                unsigned e = __hip_atomic_load(flags + (tid + 192) * 32, __ATOMIC_RELAXED, __HIP_MEMORY_SCOPE_AGENT);
                if (__all(a >= LAYER_DONE && b >= LAYER_DONE &&
                          c >= LAYER_DONE && e >= LAYER_DONE)) break;
                __builtin_amdgcn_s_sleep(1);
                if (++n > SPIN_LIM) break;
            }
        }
        __syncthreads();
        if (tid < 64) {                     // re-poison all parities (own region)
            #pragma unroll
            for (int p = 0; p < 8; ++p) {
                unsigned long long* pd =
                    hbuf64 + ((long long)(((p * 2 + d) * 2 + bg) * 64 + nt)) * 64 + tid;
                __hip_atomic_store(pd, POISON, __ATOMIC_RELAXED, __HIP_MEMORY_SCOPE_AGENT);
            }
        }
        asm volatile("s_waitcnt vmcnt(0)" ::: "memory");
        __syncthreads();
        if (tid == 0)
            __hip_atomic_store(flags + bid * 32, POISON_DONE,
                               __ATOMIC_RELAXED, __HIP_MEMORY_SCOPE_AGENT);
        if (tid < 64) {                     // phase 2: all poisons visible
            int n = 0;
            for (;;) {
                unsigned a = __hip_atomic_load(flags + tid * 32,         __ATOMIC_RELAXED, __HIP_MEMORY_SCOPE_AGENT);
                unsigned b = __hip_atomic_load(flags + (tid + 64) * 32,  __ATOMIC_RELAXED, __HIP_MEMORY_SCOPE_AGENT);
                unsigned c = __hip_atomic_load(flags + (tid + 128) * 32, __ATOMIC_RELAXED, __HIP_MEMORY_SCOPE_AGENT);
                unsigned e = __hip_atomic_load(flags + (tid + 192) * 32, __ATOMIC_RELAXED, __HIP_MEMORY_SCOPE_AGENT);
                if (__all(a >= POISON_DONE && b >= POISON_DONE &&
                          c >= POISON_DONE && e >= POISON_DONE)) break;
                __builtin_amdgcn_s_sleep(1);
                if (++n > SPIN_LIM) break;
            }
        }
        __syncthreads();
        __threadfence();                    // inv stale lines before cached reads
    }

    layer_steps<1024>(d, bg, nt, tid, tokens, embB, hs0,
                      wp1 + (long long)(d * 64 + nt) * 48 * 1024,
                      bb1 + (long long)d * 2048,
                      hs1, hbuf64, wlds, Gred, tok_s);
}

// ---------------------------------------------------------------------------
// feats = hs1(bf16) @ lin_w^T + lin_b   (64-row tiles, N=32)
// ---------------------------------------------------------------------------
__global__ __launch_bounds__(256) void gemm_feats(
    const unsigned short* __restrict__ A,      // [M][1024] bf16
    const float* __restrict__ W,               // [32][1024]
    const float* __restrict__ bias,
    float* __restrict__ C,
    int M, int N, int K)
{
    __shared__ __align__(16) float As[64][34];
    __shared__ __align__(16) float Ws[32][68];

    const int m0 = blockIdx.y * 64;
    const int tid = threadIdx.x;
    const int tr = tid >> 4;
    const int tc = tid & 15;

    float acc[4][4];
    #pragma unroll
    for (int i = 0; i < 4; ++i)
        #pragma unroll
        for (int j = 0; j < 4; ++j) acc[i][j] = 0.0f;

    for (int k0 = 0; k0 < K; k0 += 32) {
        {   // A tile: 64 rows x 32 k (bf16 -> f32)
            int row = tid >> 2, g8 = tid & 3;
            uint4 v = *(const uint4*)(A + ((long long)(m0 + row)) * 1024 + k0 + g8 * 8);
            const unsigned short* pv = (const unsigned short*)&v;
            #pragma unroll
            for (int e = 0; e < 8; ++e) As[row][g8 * 8 + e] = b2f(pv[e]);
        }
        {   // W tile: 32 rows x 32 k, transposed
            int row = tid >> 3, q2 = tid & 7;
            float4 v = *(const float4*)(W + (long long)row * K + k0 + 4 * q2);
            Ws[4*q2+0][row] = v.x; Ws[4*q2+1][row] = v.y;
            Ws[4*q2+2][row] = v.z; Ws[4*q2+3][row] = v.w;
        }
        __syncthreads();
        #pragma unroll 8
        for (int kk = 0; kk < 32; ++kk) {
            float a0 = As[4*tr+0][kk], a1 = As[4*tr+1][kk];
            float a2 = As[4*tr+2][kk], a3 = As[4*tr+3][kk];
            float4 wv = *(const float4*)&Ws[kk][4*tc];
            acc[0][0] += a0*wv.x; acc[0][1] += a0*wv.y; acc[0][2] += a0*wv.z; acc[0][3] += a0*wv.w;
            acc[1][0] += a1*wv.x; acc[1][1] += a1*wv.y; acc[1][2] += a1*wv.z; acc[1][3] += a1*wv.w;
            acc[2][0] += a2*wv.x; acc[2][1] += a2*wv.y; acc[2][2] += a2*wv.z; acc[2][3] += a2*wv.w;
            acc[3][0] += a3*wv.x; acc[3][1] += a3*wv.y; acc[3][2] += a3*wv.z; acc[3][3] += a3*wv.w;
        }
        __syncthreads();
    }
    #pragma unroll
    for (int i = 0; i < 4; ++i) {
        int m = m0 + 4*tr + i;
        #pragma unroll
        for (int j = 0; j < 4; ++j) {
            int n = 4*tc + j;
            if (n < N) C[(long long)m * N + n] = acc[i][j] + bias[n];
        }
    }
}

// ---------------------------------------------------------------------------
// CRF: forward logsumexp scan + log_z + gold score + loss, one block per b.
// ---------------------------------------------------------------------------
__global__ __launch_bounds__(1024) void crf_kernel(
    const float* __restrict__ feats,
    const float* __restrict__ trans,
    const int*   __restrict__ tokens,
    const int*   __restrict__ tags,
    const int*   __restrict__ lengths,
    float* __restrict__ out)
{
    const int b = blockIdx.x;
    const int tid = threadIdx.x;
    __shared__ float tr_s[KTAGS*KTAGS];
    __shared__ float score_s[KTAGS];
    __shared__ float emit_s[KTAGS];
    __shared__ float red_s[16];
    __shared__ float logz_s;

    tr_s[tid] = trans[tid];
    if (tid < KTAGS) score_s[tid] = (tid == START_TAG) ? 0.0f : NEGV;
    __syncthreads();

    const int i = tid >> 5, j = tid & 31;
    for (int t = 0; t < T_STEPS; ++t) {
        if (tid < KTAGS) emit_s[tid] = feats[((long long)t*BATCH + b)*KTAGS + tid];
        __syncthreads();
        float e = score_s[j] + tr_s[i*KTAGS + j];
        float m = e;
        m = fmaxf(m, __shfl_xor(m, 1));  m = fmaxf(m, __shfl_xor(m, 2));
        m = fmaxf(m, __shfl_xor(m, 4));  m = fmaxf(m, __shfl_xor(m, 8));
        m = fmaxf(m, __shfl_xor(m, 16));
        float p = __expf(e - m);
        p += __shfl_xor(p, 1); p += __shfl_xor(p, 2); p += __shfl_xor(p, 4);
        p += __shfl_xor(p, 8); p += __shfl_xor(p, 16);
        float nv = m + __logf(p) + emit_s[i];
        int msk = tokens[(long long)t*BATCH + b] > 0;
        __syncthreads();
        if (j == 0) score_s[i] = msk ? nv : score_s[i];
        __syncthreads();
    }

    if (tid < KTAGS) {
        float v = score_s[tid] + tr_s[END_TAG*KTAGS + tid];
        float m = v;
        m = fmaxf(m, __shfl_xor(m, 1));  m = fmaxf(m, __shfl_xor(m, 2));
        m = fmaxf(m, __shfl_xor(m, 4));  m = fmaxf(m, __shfl_xor(m, 8));
        m = fmaxf(m, __shfl_xor(m, 16));
        float p = __expf(v - m);
        p += __shfl_xor(p, 1); p += __shfl_xor(p, 2); p += __shfl_xor(p, 4);
        p += __shfl_xor(p, 8); p += __shfl_xor(p, 16);
        if (tid == 0) logz_s = m + __logf(p);
    }
    __syncthreads();

    float val = 0.0f;
    if (tid < T_STEPS) {
        int t = tid;
        int cur  = tags[(long long)t*BATCH + b];
        int prev = (t == 0) ? START_TAG : tags[(long long)(t-1)*BATCH + b];
        int msk  = tokens[(long long)t*BATCH + b] > 0;
        if (msk) val = tr_s[cur*KTAGS + prev]
                     + feats[((long long)t*BATCH + b)*KTAGS + cur];
    }
    val += __shfl_xor(val, 1);  val += __shfl_xor(val, 2);
    val += __shfl_xor(val, 4);  val += __shfl_xor(val, 8);
    val += __shfl_xor(val, 16); val += __shfl_xor(val, 32);
    int wave = tid >> 6, lane = tid & 63;
    if (lane == 0) red_s[wave] = val;
    __syncthreads();
    if (tid == 0) {
        float g = 0.0f;
        #pragma unroll
        for (int w = 0; w < 16; ++w) g += red_s[w];
        g += tr_s[END_TAG*KTAGS + tags[(long long)(T_STEPS-1)*BATCH + b]];
        atomicAdd(out, (logz_s - g) / (float)lengths[b]);
    }
}

// ---------------------------------------------------------------------------
extern "C" void kernel_launch(void* const* d_in, const int* in_sizes, int n_in,
                              void* d_out, int out_size, void* d_ws, size_t ws_size,
                              hipStream_t stream) {
    const int*   tokens  = (const int*)  d_in[0];
    const int*   tags    = (const int*)  d_in[1];
    const int*   lengths = (const int*)  d_in[2];
    const float* embed   = (const float*)d_in[3];
    const float* wih0    = (const float*)d_in[4];
    const float* whh0    = (const float*)d_in[5];
    const float* b0      = (const float*)d_in[6];
    const float* wih1    = (const float*)d_in[7];
    const float* whh1    = (const float*)d_in[8];
    const float* b1      = (const float*)d_in[9];
    const float* lin_w   = (const float*)d_in[10];
    const float* lin_b   = (const float*)d_in[11];
    const float* trans   = (const float*)d_in[12];

    // Workspace layout (total ~123.2 MiB footprint, unchanged).
    // Flags (64 KiB) and the 8-parity h-exchange buffers (1 MiB) live INSIDE
    // the feats buffer (2 MiB): feats is dead until gemm_feats runs (after
    // lstm_mfma completes), and gemm overwrites the whole 2 MiB.
    char* ws = (char*)d_ws;
    unsigned short* hs0   = (unsigned short*)(ws);                   // 33,554,432
    unsigned short* hs1   = (unsigned short*)(ws +  33554432ULL);    // 33,554,432
    unsigned short* embB  = (unsigned short*)(ws +  67108864ULL);    // 32,768,000
    unsigned short* wp0   = (unsigned short*)(ws +  99876864ULL);    //  8,388,608
    unsigned short* wp1   = (unsigned short*)(ws + 108265472ULL);    // 12,582,912
    float*          feats = (float*)        (ws + 120848384ULL);     //  2,097,152
    unsigned int*   flagsP = (unsigned int*)feats;                   // 65,536
    unsigned long long* hbufP = (unsigned long long*)((char*)feats + 65536); // 1,048,576

    float* out = (float*)d_out;

    init_zero<<<dim3(512), 256, 0, stream>>>(flagsP, hbufP, out);
    convert_embed<<<dim3(16000), 256, 0, stream>>>(embed, embB);
    pack_w<<<dim3(2048), 256, 0, stream>>>(wih0, whh0, 512,  wp0);
    pack_w<<<dim3(3072), 256, 0, stream>>>(wih1, whh1, 1024, wp1);

    lstm_mfma<<<dim3(NBLK), 256, 0, stream>>>(
        tokens, embB, wp0, wp1, b0, b1, hs0, hs1, hbufP, flagsP);

    gemm_feats<<<dim3(1, 256, 1), 256, 0, stream>>>(
        hs1, lin_w, lin_b, feats, T_STEPS*BATCH, KTAGS, 2*HID);

    crf_kernel<<<dim3(BATCH), 1024, 0, stream>>>(feats, trans, tokens, tags,
                                                 lengths, out);
}

// Round 7
// 2311.745 us; speedup vs baseline: 1.0741x; 1.0741x over previous
//
#include <hip/hip_runtime.h>
#include <math.h>

// Problem constants (V,E,H,K,T,B) = (32000, 512, 512, 32, 256, 64)
#define T_STEPS 256
#define BATCH   64
#define HID     512
#define KTAGS   32
#define NEGV    -100000.0f
#define START_TAG 30
#define END_TAG   31

#define NBLK      256
#define SPIN_LIM  (1 << 24)
#define LAYER_DONE  300u
#define POISON_DONE 301u
#define POISON    0xFFFFFFFFFFFFFFFFULL

typedef __attribute__((ext_vector_type(8))) short short8;
typedef __attribute__((ext_vector_type(4))) float f32x4;

union V16 { uint4 u; short8 s; };
union HQ  { unsigned long long q[2]; short8 s; };

static __device__ __forceinline__ unsigned short f2b(float f) {
    unsigned u = __float_as_uint(f);
    return (unsigned short)((u + 0x7fffu + ((u >> 16) & 1u)) >> 16);
}
static __device__ __forceinline__ float b2f(unsigned short us) {
    return __uint_as_float(((unsigned)us) << 16);
}

// ---------------------------------------------------------------------------
// Init: poison h-exchange buffers (8 par x 2 d x 2 bg x 64 nt x 64 u64 = 1MB),
// zero padded flag region, zero d_out. Agent-scope stores.
// ---------------------------------------------------------------------------
__global__ __launch_bounds__(256) void init_zero(unsigned int* __restrict__ flags,
                                                 unsigned long long* __restrict__ hbuf,
                                                 float* __restrict__ out)
{
    int i = blockIdx.x * 256 + threadIdx.x;
    if (i < 131072)
        __hip_atomic_store(hbuf + i, POISON, __ATOMIC_RELAXED, __HIP_MEMORY_SCOPE_AGENT);
    if (i < 16384)
        __hip_atomic_store(flags + i, 0u, __ATOMIC_RELAXED, __HIP_MEMORY_SCOPE_AGENT);
    if (i == 0)
        __hip_atomic_store(out, 0.0f, __ATOMIC_RELAXED, __HIP_MEMORY_SCOPE_AGENT);
}

// ---------------------------------------------------------------------------
// embed fp32 -> bf16 (one-time, 16.4M elements)
// ---------------------------------------------------------------------------
__global__ __launch_bounds__(256) void convert_embed(const float* __restrict__ src,
                                                     unsigned short* __restrict__ dst)
{
    long long i = ((long long)blockIdx.x * 256 + threadIdx.x) * 4;
    if (i >= (long long)32000 * 512) return;
    float4 v = *(const float4*)(src + i);
    ushort4 o;
    o.x = f2b(v.x); o.y = f2b(v.y); o.z = f2b(v.z); o.w = f2b(v.w);
    *(ushort4*)(dst + i) = o;
}

// ---------------------------------------------------------------------------
// Pack Wih|Whh (fp32) into bf16 MFMA B-fragment stream for the
// 64-col-block partition. Stream: [d][nt(64)][kt(KT)][nf(2)][lane(64)][j(8)].
// Block (d,nt) owns h-cols nt*8..nt*8+7 => 32 gate cols; frag nf covers
// block-cols bc = nf*16 + (lane&15), bc -> gate g = bc>>3, cc = bc&7,
// weight row r = g*512 + nt*8 + cc; k = kt*32 + (lane>>4)*8 + j.
// kt<xKt -> Wih, else Whh. Thread t == flat 16B granule => coalesced stores.
// ---------------------------------------------------------------------------
__global__ __launch_bounds__(256) void pack_w(const float* __restrict__ wih,
                                              const float* __restrict__ whh,
                                              int xK,
                                              unsigned short* __restrict__ wpack)
{
    const int xKt = xK >> 5, KT = xKt + 16;
    long long t = (long long)blockIdx.x * 256 + threadIdx.x;
    if (t >= (long long)2 * 64 * KT * 2 * 64) return;
    int lane = (int)(t & 63);
    long long rest = t >> 6;
    int nf = (int)(rest & 1); rest >>= 1;
    int kt = (int)(rest % KT); rest /= KT;
    int nt = (int)(rest % 64);
    int d  = (int)(rest / 64);
    int c = lane & 15, q = lane >> 4;
    int bc = nf * 16 + c;
    int r = (bc >> 3) * 512 + nt * 8 + (bc & 7);
    const float* src;
    if (kt < xKt) src = wih + ((long long)d * 2048 * xK + (long long)r * xK + kt * 32 + q * 8);
    else          src = whh + ((long long)d * 2048 * 512 + (long long)r * 512 + (kt - xKt) * 32 + q * 8);
    float4 v0 = *(const float4*)src;
    float4 v1 = *(const float4*)(src + 4);
    unsigned short o[8] = { f2b(v0.x), f2b(v0.y), f2b(v0.z), f2b(v0.w),
                            f2b(v1.x), f2b(v1.y), f2b(v1.z), f2b(v1.w) };
    *(uint4*)(wpack + t * 8) = *(const uint4*)o;
}

// ---------------------------------------------------------------------------
// One BiLSTM layer's step loop, templated on input width XK.
// Pipeline per step (vmcnt FIFO is in-order retire):
//   [all A loads] -> [16 prime h loads] -> [X MFMAs: A + LDS-B; counted
//   vmcnt for A leaves primes in flight] -> [branchless bulk validate:
//   check-all / __all / reload-all, no divergent per-word branches, no
//   sleep for first passes] -> [H MFMAs from LDS] -> [Gred write (parity
//   dbuf), ONE barrier, float4 gate reads] -> [gates] -> [shfl publish].
// Gred layout: [par][wave][row][hc*4+g] stride 36 f32 (16B aligned rows):
// gate phase reads one float4 per wave-slice instead of 16 conflicted b32.
// All arithmetic (k-order per acc, reduce order, gate math, pack layout,
// store addresses, atomic scopes) identical to prior passing version.
// ---------------------------------------------------------------------------
template<int XK>
static __device__ __forceinline__ void layer_steps(
    const int d, const int bg, const int nt, const int tid,
    const int* __restrict__ tokens,
    const unsigned short* __restrict__ embB,
    const unsigned short* __restrict__ hs_in,   // L1 input rows (null for L0)
    const unsigned short* __restrict__ wp,      // block's packed weight base
    const float* __restrict__ bia,
    unsigned short* __restrict__ hso,
    unsigned long long* __restrict__ hbuf64,
    uint4* __restrict__ wlds,                   // [KT][2][64] uint4 (LDS)
    float (&Gred)[2][4][32][36])
{
    constexpr bool L0  = (XK == 512);
    constexpr int  xKt = XK >> 5;
    constexpr int  KT  = xKt + 16;
    constexpr int  nX  = xKt >> 2;             // X-phase kts per wave (4 or 8)

    const int w = tid >> 6, lane = tid & 63;
    const int lm = lane & 15, q = lane >> 4;
    const int brow = tid >> 3, hc = tid & 7;   // gate-phase cell (row, hcol)

    // ALL weights -> LDS (once per layer)
    const uint4* wp4 = (const uint4*)wp;
    for (int j = tid; j < KT * 128; j += 256)
        wlds[j] = wp4[j];

    float breg[4];
    #pragma unroll
    for (int g = 0; g < 4; ++g) breg[g] = bia[g * 512 + nt * 8 + hc];
    float creg = 0.0f;

    __syncthreads();

    for (int s = 0; s < T_STEPS; ++s) {
        const int tt = d ? (T_STEPS - 1 - s) : s;
        const int p  = s & 1;

        // A-row base pointers (lane rows mt*16+lm); per-lane token loads
        const unsigned short* xr[2];
        #pragma unroll
        for (int mt = 0; mt < 2; ++mt) {
            int m = mt * 16 + lm;
            if (L0) {
                int tok = tokens[tt * BATCH + bg * 32 + m];
                xr[mt] = embB + (long long)tok * 512;
            } else {
                xr[mt] = hs_in + ((long long)tt * 64 + bg * 32 + m) * 1024;
            }
        }

        // ---------------- issue ALL A loads (unrolled, in flight) ----------
        uint4 av[nX][2];
        #pragma unroll
        for (int i = 0; i < nX; ++i) {
            const int kt = w * nX + i;
            #pragma unroll
            for (int mt = 0; mt < 2; ++mt)
                av[i][mt] = *(const uint4*)(xr[mt] + kt * 32 + q * 8);
        }

        // ---------------- prime-burst h(s-1) (after A loads in FIFO) -------
        HQ hq[4][2];
        const unsigned long long* hbq =
            hbuf64 + (long long)(((((s - 1) & 7) * 2 + d) * 2 + bg)) * 4096;
        if (s > 0) {
            #pragma unroll
            for (int i = 0; i < 4; ++i) {
                const int kth = w * 4 + i;
                #pragma unroll
                for (int mt = 0; mt < 2; ++mt) {
                    const int base = (kth * 4 + q) * 64 + (mt * 16 + lm) * 2;
                    hq[i][mt].q[0] = __hip_atomic_load(hbq + base,     __ATOMIC_RELAXED, __HIP_MEMORY_SCOPE_AGENT);
                    hq[i][mt].q[1] = __hip_atomic_load(hbq + base + 1, __ATOMIC_RELAXED, __HIP_MEMORY_SCOPE_AGENT);
                }
            }
        }

        // ---------------- X MFMAs (B from LDS; primes stay in flight) ------
        f32x4 acc[2][2];
        #pragma unroll
        for (int mt = 0; mt < 2; ++mt)
            #pragma unroll
            for (int nf = 0; nf < 2; ++nf) acc[mt][nf] = (f32x4)0.0f;

        #pragma unroll
        for (int i = 0; i < nX; ++i) {
            const int kt = w * nX + i;
            V16 a0, a1, b0, b1;
            a0.u = av[i][0]; a1.u = av[i][1];
            b0.u = wlds[(kt * 2 + 0) * 64 + lane];
            b1.u = wlds[(kt * 2 + 1) * 64 + lane];
            acc[0][0] = __builtin_amdgcn_mfma_f32_16x16x32_bf16(a0.s, b0.s, acc[0][0], 0, 0, 0);
            acc[0][1] = __builtin_amdgcn_mfma_f32_16x16x32_bf16(a0.s, b1.s, acc[0][1], 0, 0, 0);
            acc[1][0] = __builtin_amdgcn_mfma_f32_16x16x32_bf16(a1.s, b0.s, acc[1][0], 0, 0, 0);
            acc[1][1] = __builtin_amdgcn_mfma_f32_16x16x32_bf16(a1.s, b1.s, acc[1][1], 0, 0, 0);
        }

        // -------- branchless bulk validate, then H MFMAs -------------------
        if (s > 0) {
            int pass = 0;
            for (;;) {
                int ok = 1;
                #pragma unroll
                for (int i = 0; i < 4; ++i)
                    #pragma unroll
                    for (int mt = 0; mt < 2; ++mt)
                        ok &= (hq[i][mt].q[0] != POISON) && (hq[i][mt].q[1] != POISON);
                if (__all(ok)) break;
                if (++pass > SPIN_LIM) break;
                if (pass >= 3) __builtin_amdgcn_s_sleep(1);
                #pragma unroll
                for (int i = 0; i < 4; ++i) {
                    const int kth = w * 4 + i;
                    #pragma unroll
                    for (int mt = 0; mt < 2; ++mt) {
                        const int base = (kth * 4 + q) * 64 + (mt * 16 + lm) * 2;
                        hq[i][mt].q[0] = __hip_atomic_load(hbq + base,     __ATOMIC_RELAXED, __HIP_MEMORY_SCOPE_AGENT);
                        hq[i][mt].q[1] = __hip_atomic_load(hbq + base + 1, __ATOMIC_RELAXED, __HIP_MEMORY_SCOPE_AGENT);
                    }
                }
            }

            #pragma unroll
            for (int i = 0; i < 4; ++i) {
                const int kth = w * 4 + i;
                V16 b0, b1;
                b0.u = wlds[((xKt + kth) * 2 + 0) * 64 + lane];
                b1.u = wlds[((xKt + kth) * 2 + 1) * 64 + lane];
                acc[0][0] = __builtin_amdgcn_mfma_f32_16x16x32_bf16(hq[i][0].s, b0.s, acc[0][0], 0, 0, 0);
                acc[0][1] = __builtin_amdgcn_mfma_f32_16x16x32_bf16(hq[i][0].s, b1.s, acc[0][1], 0, 0, 0);
                acc[1][0] = __builtin_amdgcn_mfma_f32_16x16x32_bf16(hq[i][1].s, b0.s, acc[1][0], 0, 0, 0);
                acc[1][1] = __builtin_amdgcn_mfma_f32_16x16x32_bf16(hq[i][1].s, b1.s, acc[1][1], 0, 0, 0);
            }
        }

        // ------- K-reduce: parity-dbuf Gred, ONE barrier, float4 reads -----
        #pragma unroll
        for (int mt = 0; mt < 2; ++mt)
            #pragma unroll
            for (int nf = 0; nf < 2; ++nf)
                #pragma unroll
                for (int r = 0; r < 4; ++r) {
                    const int row = mt * 16 + q * 4 + r;
                    const int c   = nf * 16 + lm;          // gate-col 0..31
                    const int cp  = (c & 7) * 4 + (c >> 3); // [hc][g] layout
                    Gred[p][w][row][cp] = acc[mt][nf][r];
                }
        __syncthreads();

        float vg[4];
        {
            const float4 g0 = *(const float4*)&Gred[p][0][brow][hc * 4];
            const float4 g1 = *(const float4*)&Gred[p][1][brow][hc * 4];
            const float4 g2 = *(const float4*)&Gred[p][2][brow][hc * 4];
            const float4 g3 = *(const float4*)&Gred[p][3][brow][hc * 4];
            vg[0] = breg[0] + g0.x + g1.x + g2.x + g3.x;
            vg[1] = breg[1] + g0.y + g1.y + g2.y + g3.y;
            vg[2] = breg[2] + g0.z + g1.z + g2.z + g3.z;
            vg[3] = breg[3] + g0.w + g1.w + g2.w + g3.w;
        }
        const float si = 1.0f / (1.0f + __expf(-vg[0]));
        const float sf = 1.0f / (1.0f + __expf(-vg[1]));
        const float so = 1.0f / (1.0f + __expf(-vg[3]));
        const float cn = sf * creg + si * tanhf(vg[2]);
        const float hn = so * tanhf(cn);
        creg = cn;

        // ------- publish h via shfl pack (data store IS the signal) --------
        unsigned pv = (unsigned)f2b(hn);
        unsigned p2 = pv | (__shfl_xor(pv, 1) << 16);
        unsigned long long hv = (unsigned long long)p2
                              | ((unsigned long long)__shfl_xor(p2, 2) << 32);
        if ((tid & 3) == 0) {
            const int row = brow, cq = hc >> 2;
            unsigned long long* dst =
                hbuf64 + ((long long)((((s & 7) * 2 + d) * 2 + bg) * 64 + nt)) * 64 + row * 2 + cq;
            __hip_atomic_store(dst, hv, __ATOMIC_RELAXED, __HIP_MEMORY_SCOPE_AGENT);
            *(unsigned long long*)(hso + ((long long)tt * 64 + bg * 32 + row) * 1024
                                       + d * 512 + nt * 8 + cq * 4) = hv;
            unsigned long long* pdst =
                hbuf64 + ((long long)(((((s + 2) & 7) * 2 + d) * 2 + bg) * 64 + nt)) * 64 + row * 2 + cq;
            __hip_atomic_store(pdst, POISON, __ATOMIC_RELAXED, __HIP_MEMORY_SCOPE_AGENT);
        }
        // no per-step drain / flag / extra barrier: consumers self-validate
    }
}

// ---------------------------------------------------------------------------
// Persistent BiLSTM, MFMA edition — batch-grouped partition (2d x 2bg x 64nt,
// block owns 32 rows x 8 h-cols), data-is-signal poison exchange, all-LDS
// weights, parity-dbuf Gred (1 barrier/step). Layer boundary: two-phase flag
// barrier + re-poison. LDS: 96KB weights + 36KB Gred (1 block/CU).
// ---------------------------------------------------------------------------
__global__ __launch_bounds__(256, 1) void lstm_mfma(
    const int* __restrict__ tokens,
    const unsigned short* __restrict__ embB,   // [32000][512] bf16
    const unsigned short* __restrict__ wp0,    // packed L0 weights
    const unsigned short* __restrict__ wp1,    // packed L1 weights
    const float* __restrict__ bb0, const float* __restrict__ bb1,
    unsigned short* __restrict__ hs0,          // [T][B][1024] bf16
    unsigned short* __restrict__ hs1,
    unsigned long long* __restrict__ hbuf64,   // [8][2][2][64][32][2] u64
    unsigned int* __restrict__ flags)          // 256 x 32 u32 (128B pad/line)
{
    __shared__ uint4 wlds[6144];                           // 96KB
    __shared__ __align__(16) float Gred[2][4][32][36];     // 36KB

    const int bid = blockIdx.x;
    const int d   = bid >> 7;
    const int bg  = (bid >> 6) & 1;
    const int nt  = bid & 63;
    const int tid = threadIdx.x;

    layer_steps<512>(d, bg, nt, tid, tokens, embB, (const unsigned short*)nullptr,
                     wp0 + (long long)(d * 64 + nt) * 32 * 1024,
                     bb0 + (long long)d * 2048,
                     hs0, hbuf64, wlds, Gred);

    // ------------- layer boundary: two-phase barrier ------------------------
    {
        __threadfence();                    // wb dirty hs0 out of local L2
        __syncthreads();
        if (tid == 0)
            __hip_atomic_store(flags + bid * 32, LAYER_DONE,
                               __ATOMIC_RELAXED, __HIP_MEMORY_SCOPE_AGENT);
        if (tid < 64) {                     // phase 1: all 256 blocks done
            int n = 0;
            for (;;) {
                unsigned a = __hip_atomic_load(flags + tid * 32,         __ATOMIC_RELAXED, __HIP_MEMORY_SCOPE_AGENT);
                unsigned b = __hip_atomic_load(flags + (tid + 64) * 32,  __ATOMIC_RELAXED, __HIP_MEMORY_SCOPE_AGENT);
                unsigned c = __hip_atomic_load(flags + (tid + 128) * 32, __ATOMIC_RELAXED, __HIP_MEMORY_SCOPE_AGENT);
                unsigned e = __hip_atomic_load(flags + (tid + 192) * 32, __ATOMIC_RELAXED, __HIP_MEMORY_SCOPE_AGENT);
                if (__all(a >= LAYER_DONE && b >= LAYER_DONE &&
                          c >= LAYER_DONE && e >= LAYER_DONE)) break;
                __builtin_amdgcn_s_sleep(1);
                if (++n > SPIN_LIM) break;
            }
        }
        __syncthreads();
        if (tid < 64) {                     // re-poison all parities (own region)
            #pragma unroll
            for (int pp = 0; pp < 8; ++pp) {
                unsigned long long* pd =
                    hbuf64 + ((long long)(((pp * 2 + d) * 2 + bg) * 64 + nt)) * 64 + tid;
                __hip_atomic_store(pd, POISON, __ATOMIC_RELAXED, __HIP_MEMORY_SCOPE_AGENT);
            }
        }
        asm volatile("s_waitcnt vmcnt(0)" ::: "memory");
        __syncthreads();
        if (tid == 0)
            __hip_atomic_store(flags + bid * 32, POISON_DONE,
                               __ATOMIC_RELAXED, __HIP_MEMORY_SCOPE_AGENT);
        if (tid < 64) {                     // phase 2: all poisons visible
            int n = 0;
            for (;;) {
                unsigned a = __hip_atomic_load(flags + tid * 32,         __ATOMIC_RELAXED, __HIP_MEMORY_SCOPE_AGENT);
                unsigned b = __hip_atomic_load(flags + (tid + 64) * 32,  __ATOMIC_RELAXED, __HIP_MEMORY_SCOPE_AGENT);
                unsigned c = __hip_atomic_load(flags + (tid + 128) * 32, __ATOMIC_RELAXED, __HIP_MEMORY_SCOPE_AGENT);
                unsigned e = __hip_atomic_load(flags + (tid + 192) * 32, __ATOMIC_RELAXED, __HIP_MEMORY_SCOPE_AGENT);
                if (__all(a >= POISON_DONE && b >= POISON_DONE &&
                          c >= POISON_DONE && e >= POISON_DONE)) break;
                __builtin_amdgcn_s_sleep(1);
                if (++n > SPIN_LIM) break;
            }
        }
        __syncthreads();
        __threadfence();                    // inv stale lines before cached reads
    }

    layer_steps<1024>(d, bg, nt, tid, tokens, embB, hs0,
                      wp1 + (long long)(d * 64 + nt) * 48 * 1024,
                      bb1 + (long long)d * 2048,
                      hs1, hbuf64, wlds, Gred);
}

// ---------------------------------------------------------------------------
// feats = hs1(bf16) @ lin_w^T + lin_b   (64-row tiles, N=32)
// ---------------------------------------------------------------------------
__global__ __launch_bounds__(256) void gemm_feats(
    const unsigned short* __restrict__ A,      // [M][1024] bf16
    const float* __restrict__ W,               // [32][1024]
    const float* __restrict__ bias,
    float* __restrict__ C,
    int M, int N, int K)
{
    __shared__ __align__(16) float As[64][34];
    __shared__ __align__(16) float Ws[32][68];

    const int m0 = blockIdx.y * 64;
    const int tid = threadIdx.x;
    const int tr = tid >> 4;
    const int tc = tid & 15;

    float acc[4][4];
    #pragma unroll
    for (int i = 0; i < 4; ++i)
        #pragma unroll
        for (int j = 0; j < 4; ++j) acc[i][j] = 0.0f;

    for (int k0 = 0; k0 < K; k0 += 32) {
        {   // A tile: 64 rows x 32 k (bf16 -> f32)
            int row = tid >> 2, g8 = tid & 3;
            uint4 v = *(const uint4*)(A + ((long long)(m0 + row)) * 1024 + k0 + g8 * 8);
            const unsigned short* pv = (const unsigned short*)&v;
            #pragma unroll
            for (int e = 0; e < 8; ++e) As[row][g8 * 8 + e] = b2f(pv[e]);
        }
        {   // W tile: 32 rows x 32 k, transposed
            int row = tid >> 3, q2 = tid & 7;
            float4 v = *(const float4*)(W + (long long)row * K + k0 + 4 * q2);
            Ws[4*q2+0][row] = v.x; Ws[4*q2+1][row] = v.y;
            Ws[4*q2+2][row] = v.z; Ws[4*q2+3][row] = v.w;
        }
        __syncthreads();
        #pragma unroll 8
        for (int kk = 0; kk < 32; ++kk) {
            float a0 = As[4*tr+0][kk], a1 = As[4*tr+1][kk];
            float a2 = As[4*tr+2][kk], a3 = As[4*tr+3][kk];
            float4 wv = *(const float4*)&Ws[kk][4*tc];
            acc[0][0] += a0*wv.x; acc[0][1] += a0*wv.y; acc[0][2] += a0*wv.z; acc[0][3] += a0*wv.w;
            acc[1][0] += a1*wv.x; acc[1][1] += a1*wv.y; acc[1][2] += a1*wv.z; acc[1][3] += a1*wv.w;
            acc[2][0] += a2*wv.x; acc[2][1] += a2*wv.y; acc[2][2] += a2*wv.z; acc[2][3] += a2*wv.w;
            acc[3][0] += a3*wv.x; acc[3][1] += a3*wv.y; acc[3][2] += a3*wv.z; acc[3][3] += a3*wv.w;
        }
        __syncthreads();
    }
    #pragma unroll
    for (int i = 0; i < 4; ++i) {
        int m = m0 + 4*tr + i;
        #pragma unroll
        for (int j = 0; j < 4; ++j) {
            int n = 4*tc + j;
            if (n < N) C[(long long)m * N + n] = acc[i][j] + bias[n];
        }
    }
}

// ---------------------------------------------------------------------------
// CRF: forward logsumexp scan + log_z + gold score + loss, one block per b.
// ---------------------------------------------------------------------------
__global__ __launch_bounds__(1024) void crf_kernel(
    const float* __restrict__ feats,
    const float* __restrict__ trans,
    const int*   __restrict__ tokens,
    const int*   __restrict__ tags,
    const int*   __restrict__ lengths,
    float* __restrict__ out)
{
    const int b = blockIdx.x;
    const int tid = threadIdx.x;
    __shared__ float tr_s[KTAGS*KTAGS];
    __shared__ float score_s[KTAGS];
    __shared__ float emit_s[KTAGS];
    __shared__ float red_s[16];
    __shared__ float logz_s;

    tr_s[tid] = trans[tid];
    if (tid < KTAGS) score_s[tid] = (tid == START_TAG) ? 0.0f : NEGV;
    __syncthreads();

    const int i = tid >> 5, j = tid & 31;
    for (int t = 0; t < T_STEPS; ++t) {
        if (tid < KTAGS) emit_s[tid] = feats[((long long)t*BATCH + b)*KTAGS + tid];
        __syncthreads();
        float e = score_s[j] + tr_s[i*KTAGS + j];
        float m = e;
        m = fmaxf(m, __shfl_xor(m, 1));  m = fmaxf(m, __shfl_xor(m, 2));
        m = fmaxf(m, __shfl_xor(m, 4));  m = fmaxf(m, __shfl_xor(m, 8));
        m = fmaxf(m, __shfl_xor(m, 16));
        float p = __expf(e - m);
        p += __shfl_xor(p, 1); p += __shfl_xor(p, 2); p += __shfl_xor(p, 4);
        p += __shfl_xor(p, 8); p += __shfl_xor(p, 16);
        float nv = m + __logf(p) + emit_s[i];
        int msk = tokens[(long long)t*BATCH + b] > 0;
        __syncthreads();
        if (j == 0) score_s[i] = msk ? nv : score_s[i];
        __syncthreads();
    }

    if (tid < KTAGS) {
        float v = score_s[tid] + tr_s[END_TAG*KTAGS + tid];
        float m = v;
        m = fmaxf(m, __shfl_xor(m, 1));  m = fmaxf(m, __shfl_xor(m, 2));
        m = fmaxf(m, __shfl_xor(m, 4));  m = fmaxf(m, __shfl_xor(m, 8));
        m = fmaxf(m, __shfl_xor(m, 16));
        float p = __expf(v - m);
        p += __shfl_xor(p, 1); p += __shfl_xor(p, 2); p += __shfl_xor(p, 4);
        p += __shfl_xor(p, 8); p += __shfl_xor(p, 16);
        if (tid == 0) logz_s = m + __logf(p);
    }
    __syncthreads();

    float val = 0.0f;
    if (tid < T_STEPS) {
        int t = tid;
        int cur  = tags[(long long)t*BATCH + b];
        int prev = (t == 0) ? START_TAG : tags[(long long)(t-1)*BATCH + b];
        int msk  = tokens[(long long)t*BATCH + b] > 0;
        if (msk) val = tr_s[cur*KTAGS + prev]
                     + feats[((long long)t*BATCH + b)*KTAGS + cur];
    }
    val += __shfl_xor(val, 1);  val += __shfl_xor(val, 2);
    val += __shfl_xor(val, 4);  val += __shfl_xor(val, 8);
    val += __shfl_xor(val, 16); val += __shfl_xor(val, 32);
    int wave = tid >> 6, lane = tid & 63;
    if (lane == 0) red_s[wave] = val;
    __syncthreads();
    if (tid == 0) {
        float g = 0.0f;
        #pragma unroll
        for (int w = 0; w < 16; ++w) g += red_s[w];
        g += tr_s[END_TAG*KTAGS + tags[(long long)(T_STEPS-1)*BATCH + b]];
        atomicAdd(out, (logz_s - g) / (float)lengths[b]);
    }
}

// ---------------------------------------------------------------------------
extern "C" void kernel_launch(void* const* d_in, const int* in_sizes, int n_in,
                              void* d_out, int out_size, void* d_ws, size_t ws_size,
                              hipStream_t stream) {
    const int*   tokens  = (const int*)  d_in[0];
    const int*   tags    = (const int*)  d_in[1];
    const int*   lengths = (const int*)  d_in[2];
    const float* embed   = (const float*)d_in[3];
    const float* wih0    = (const float*)d_in[4];
    const float* whh0    = (const float*)d_in[5];
    const float* b0      = (const float*)d_in[6];
    const float* wih1    = (const float*)d_in[7];
    const float* whh1    = (const float*)d_in[8];
    const float* b1      = (const float*)d_in[9];
    const float* lin_w   = (const float*)d_in[10];
    const float* lin_b   = (const float*)d_in[11];
    const float* trans   = (const float*)d_in[12];

    // Workspace layout (total ~123.2 MiB footprint, unchanged).
    // Flags (64 KiB) and the 8-parity h-exchange buffers (1 MiB) live INSIDE
    // the feats buffer (2 MiB): feats is dead until gemm_feats runs (after
    // lstm_mfma completes), and gemm overwrites the whole 2 MiB.
    char* ws = (char*)d_ws;
    unsigned short* hs0   = (unsigned short*)(ws);                   // 33,554,432
    unsigned short* hs1   = (unsigned short*)(ws +  33554432ULL);    // 33,554,432
    unsigned short* embB  = (unsigned short*)(ws +  67108864ULL);    // 32,768,000
    unsigned short* wp0   = (unsigned short*)(ws +  99876864ULL);    //  8,388,608
    unsigned short* wp1   = (unsigned short*)(ws + 108265472ULL);    // 12,582,912
    float*          feats = (float*)        (ws + 120848384ULL);     //  2,097,152
    unsigned int*   flagsP = (unsigned int*)feats;                   // 65,536
    unsigned long long* hbufP = (unsigned long long*)((char*)feats + 65536); // 1,048,576

    float* out = (float*)d_out;

    init_zero<<<dim3(512), 256, 0, stream>>>(flagsP, hbufP, out);
    convert_embed<<<dim3(16000), 256, 0, stream>>>(embed, embB);
    pack_w<<<dim3(2048), 256, 0, stream>>>(wih0, whh0, 512,  wp0);
    pack_w<<<dim3(3072), 256, 0, stream>>>(wih1, whh1, 1024, wp1);

    lstm_mfma<<<dim3(NBLK), 256, 0, stream>>>(
        tokens, embB, wp0, wp1, b0, b1, hs0, hs1, hbufP, flagsP);

    gemm_feats<<<dim3(1, 256, 1), 256, 0, stream>>>(
        hs1, lin_w, lin_b, feats, T_STEPS*BATCH, KTAGS, 2*HID);

    crf_kernel<<<dim3(BATCH), 1024, 0, stream>>>(feats, trans, tokens, tags,
                                                 lengths, out);
}